// Round 6
// baseline (595.997 us; speedup 1.0000x reference)
//
#include <hip/hip_runtime.h>
#include <hip/hip_cooperative_groups.h>

namespace cg = cooperative_groups;

typedef unsigned long long u64;
typedef unsigned int u32;

#define KLVL 300
#define NPROP 900
#define MAXPROP 500
#define DDIM 213
#define EDIM 208

// anchors_px / stride (all exact in binary: /8,/16,/32)
__constant__ float c_anc[3][4][2] = {
  {{1.0f, 3.0f}, {1.375f, 4.25f}, {2.0f, 6.0f}, {2.875f, 8.5f}},
  {{2.0f, 6.0f}, {2.8125f, 8.4375f}, {4.0f, 12.0f}, {5.625f, 16.9375f}},
  {{4.0f, 12.0f}, {5.625f, 16.875f}, {8.0f, 20.0f}, {16.0f, 20.0f}},
};
__constant__ float c_scale[3] = { (float)(8.0 / 608.0), (float)(16.0 / 608.0), (float)(32.0 / 608.0) };

__device__ __forceinline__ int level_H(int lvl) { return (lvl == 0) ? 76 : ((lvl == 1) ? 38 : 19); }

// ---------------- workspace layout (bytes), identical to round 5 ----------------
#define SB_STRIDE 30336
#define SB_USED   30324
#define MASKT_STRIDE 904
#define MASK_IMG (15*904)
#define BOX_STRIDE 928
#define BOX_IMG (6*928)

#define OFF_SCORES 0               // scores dead after collect; maskT aliases
#define OFF_HIST   1945600         // hist dead after thresh; bufT aliases
#define OFF_BUFTS  1945600
#define OFF_BUFTI  2142208
#define OFF_BUFGS  2338816
#define OFF_BUFGI  2437120
#define OFF_CNTG   2535424
#define OFF_CNTT   2535680
#define OFF_THR    2535936
#define OFF_CNT    2536192
#define OFF_SELI   2594048
#define OFF_BOX    2651904
#define OFF_SRC    3008256

__device__ __forceinline__ u64 readlane_u64(u64 v, int l) {
  u32 lo = (u32)__builtin_amdgcn_readlane((int)(u32)(v & 0xFFFFFFFFull), l);
  u32 hi = (u32)__builtin_amdgcn_readlane((int)(u32)(v >> 32), l);
  return ((u64)hi << 32) | (u64)lo;
}

// idx in [0, 16*SB_STRIDE) -> (b, lvl, n); false for pad region
__device__ __forceinline__ bool decode_idx(int idx, int& b, int& lvl, int& n) {
  b = idx / SB_STRIDE;
  int off = idx - b * SB_STRIDE;
  if (off >= SB_USED) return false;
  if (off < 23104)      { lvl = 0; n = off; }
  else if (off < 28880) { lvl = 1; n = off - 23104; }
  else                  { lvl = 2; n = off - 28880; }
  return true;
}

// ---------------------------------------------------------------------------
// The whole proposal layer as ONE cooperative kernel.
// grid <= 512 blocks x 256 threads, 2 blocks/CU guaranteed by launch bounds.
// ---------------------------------------------------------------------------
__global__ __launch_bounds__(256, 2) void proposal_mega_kernel(
    const float* __restrict__ pred0, const float* __restrict__ pred1, const float* __restrict__ pred2,
    const float* __restrict__ emb0, const float* __restrict__ emb1, const float* __restrict__ emb2,
    char* __restrict__ ws, float* __restrict__ out)
{
  cg::grid_group grid = cg::this_grid();
  const int t = (int)threadIdx.x;
  const int blk = (int)blockIdx.x;
  const int nblk = (int)gridDim.x;
  const int gtid = blk * 256 + t;
  const int nthr = nblk * 256;
  const int lane = t & 63, wid = t >> 6;

  float* scores = (float*)(ws + OFF_SCORES);
  u64* maskT    = (u64*)(ws + OFF_SCORES);    // aliases scores (dead after collect)
  u32* hist     = (u32*)(ws + OFF_HIST);
  float* bufTs  = (float*)(ws + OFF_BUFTS);   // aliases hist (dead after thresh)
  int* bufTi    = (int*)(ws + OFF_BUFTI);
  float* bufGs  = (float*)(ws + OFF_BUFGS);
  int* bufGi    = (int*)(ws + OFF_BUFGI);
  u32* cntG     = (u32*)(ws + OFF_CNTG);
  u32* cntT     = (u32*)(ws + OFF_CNTT);
  int* thrT     = (int*)(ws + OFF_THR);
  int* cnt      = (int*)(ws + OFF_CNT);
  int* sel_idx  = (int*)(ws + OFF_SELI);
  float* ws_box = (float*)(ws + OFF_BOX);
  int* ws_src   = (int*)(ws + OFF_SRC);

  // shared memory (all phases; ~21 KB total)
  __shared__ float sh_gs[512];  __shared__ int sh_gi[512];
  __shared__ float sh_ts[1024]; __shared__ int sh_ti[1024];
  __shared__ float sh_sc[NPROP]; __shared__ int sh_ix[NPROP];
  __shared__ float sh_jx1[64], sh_jy1[64], sh_jx2[64], sh_jy2[64], sh_jar[64];
  __shared__ u32 sh_wt[4];
  __shared__ int sh_sT;

  // ---------------- P0: zero histogram ----------------
  for (int i = gtid; i < 48 * 2048; i += nthr) hist[i] = 0u;
  grid.sync();

  // ---------------- P1: scores + histogram ----------------
  for (int idx = gtid; idx < 16 * SB_STRIDE; idx += nthr) {
    int b, lvl, n;
    if (!decode_idx(idx, b, lvl, n)) continue;
    const float* pred = (lvl == 0) ? pred0 : ((lvl == 1) ? pred1 : pred2);
    const int N = (lvl == 0) ? 23104 : ((lvl == 1) ? 5776 : 1444);
    const float* pb = pred + (size_t)b * N * 6;
    float2 l = *reinterpret_cast<const float2*>(pb + (size_t)n * 6 + 4);
    float m = fmaxf(l.x, l.y);
    float e0 = expf(l.x - m), e1 = expf(l.y - m);
    float s = e1 / (e0 + e1);
    float sm = (s > 0.5f) ? s : 0.0f;
    scores[idx] = sm;
    if (sm > 0.0f) {
      u32 key = __float_as_uint(sm) - 0x3F000000u;
      u32 bk = min(key >> 12, 2047u);
      atomicAdd(&hist[(u32)(b * 3 + lvl) * 2048u + bk], 1u);
    }
  }
  grid.sync();

  // ---------------- P2: per-(b,lvl) threshold bucket ----------------
  for (int u = blk; u < 48; u += nblk) {
    const u32* h = hist + (size_t)u * 2048;
    u32 hv[8]; u32 part = 0;
    #pragma unroll
    for (int q = 0; q < 8; ++q) { hv[q] = h[2047 - 8 * t - q]; part += hv[q]; }
    u32 incl = part;
    #pragma unroll
    for (int off = 1; off < 64; off <<= 1) { u32 v = __shfl_up(incl, (unsigned)off, 64); if (lane >= off) incl += v; }
    if (lane == 63) sh_wt[wid] = incl;
    __syncthreads();
    u32 above = 0;
    for (int w2 = 0; w2 < wid; ++w2) above += sh_wt[w2];
    const u32 total = sh_wt[0] + sh_wt[1] + sh_wt[2] + sh_wt[3];
    if (total > 300u) {
      u32 run = above + incl - part;
      #pragma unroll
      for (int q = 0; q < 8; ++q) {
        u32 hq = hv[q];
        if (hq && run < 300u && 300u <= run + hq) sh_sT = 2047 - 8 * t - q;
        run += hq;
      }
    }
    __syncthreads();
    if (t == 0) {
      thrT[u] = (total <= 300u) ? -1 : sh_sT;
      cnt[u] = (int)min(total, 300u);
      cntG[u] = 0u; cntT[u] = 0u;
    }
    __syncthreads();
  }
  grid.sync();

  // ---------------- P3: collect greater-bucket + tie-bucket items ----------------
  for (int idx = gtid; idx < 16 * SB_STRIDE; idx += nthr) {
    int b, lvl, n;
    if (!decode_idx(idx, b, lvl, n)) continue;
    float s = scores[idx];
    if (s <= 0.0f) continue;
    u32 key = __float_as_uint(s) - 0x3F000000u;
    int bk = (int)min(key >> 12, 2047u);
    const int bl = b * 3 + lvl;
    const int T = thrT[bl];
    if (bk > T) {
      u32 p = atomicAdd(&cntG[bl], 1u);
      if (p < 512u) { bufGs[bl * 512 + p] = s; bufGi[bl * 512 + p] = n; }
    } else if (bk == T) {
      u32 p = atomicAdd(&cntT[bl], 1u);
      if (p < 1024u) { bufTs[bl * 1024 + p] = s; bufTi[bl * 1024 + p] = n; }
    }
  }
  grid.sync();

  // ---------------- P4: per-image sort (3 levels) + global rank + box decode ----------------
  for (int u = blk; u < 16; u += nblk) {
    const int b = u;
    for (int lvl = 0; lvl < 3; ++lvl) {
      const int bl = b * 3 + lvl;
      const int G = (int)min(cntG[bl], 512u);
      const int Tn = (int)min(cntT[bl], 1024u);
      const int selCnt = cnt[bl];
      for (int i = t; i < G; i += 256) { sh_gs[i] = bufGs[bl * 512 + i]; sh_gi[i] = bufGi[bl * 512 + i]; }
      for (int i = t; i < Tn; i += 256) { sh_ts[i] = bufTs[bl * 1024 + i]; sh_ti[i] = bufTi[bl * 1024 + i]; }
      __syncthreads();
      // exact (score desc, idx asc) rank-by-count
      for (int i = t; i < G; i += 256) {
        float sv = sh_gs[i]; int iv = sh_gi[i];
        int rk = 0;
        for (int j = 0; j < G; ++j) { float sj = sh_gs[j]; int ij = sh_gi[j]; rk += ((sj > sv) || (sj == sv && ij < iv)) ? 1 : 0; }
        sh_sc[lvl * KLVL + rk] = sv; sh_ix[lvl * KLVL + rk] = iv;
      }
      for (int i = t; i < Tn; i += 256) {
        float sv = sh_ts[i]; int iv = sh_ti[i];
        int rk = 0;
        for (int j = 0; j < Tn; ++j) { float sj = sh_ts[j]; int ij = sh_ti[j]; rk += ((sj > sv) || (sj == sv && ij < iv)) ? 1 : 0; }
        if (rk < selCnt - G) { sh_sc[lvl * KLVL + G + rk] = sv; sh_ix[lvl * KLVL + G + rk] = iv; }
      }
      for (int i = selCnt + t; i < KLVL; i += 256) { sh_sc[lvl * KLVL + i] = 0.0f; sh_ix[lvl * KLVL + i] = 0; }
      __syncthreads();
    }
    // persist sel_idx for the out phase
    for (int i = t; i < NPROP; i += 256) sel_idx[(size_t)b * NPROP + i] = sh_ix[i];
    const int c0 = cnt[b * 3], c1 = cnt[b * 3 + 1], c2 = cnt[b * 3 + 2];
    // global rank via 3-way sorted merge (binary search) + box decode
    for (int slot = t; slot < NPROP; slot += 256) {
      const int lvl = slot / KLVL, pos = slot - lvl * KLVL;
      const int cl = (lvl == 0) ? c0 : ((lvl == 1) ? c1 : c2);
      if (pos >= cl) continue;
      float sv = sh_sc[slot];
      u32 rank = (u32)pos;
      for (int ol = 0; ol < 3; ++ol) {
        if (ol == lvl) continue;
        int base = ol * KLVL;
        int co = (ol == 0) ? c0 : ((ol == 1) ? c1 : c2);
        int lo2 = 0, hi2 = co;
        if (ol < lvl) {  // earlier level: equal score ranks before me
          while (lo2 < hi2) { int mid = (lo2 + hi2) >> 1; if (sh_sc[base + mid] >= sv) lo2 = mid + 1; else hi2 = mid; }
        } else {         // later level: only strictly greater
          while (lo2 < hi2) { int mid = (lo2 + hi2) >> 1; if (sh_sc[base + mid] > sv) lo2 = mid + 1; else hi2 = mid; }
        }
        rank += (u32)lo2;
      }
      int n = sh_ix[slot];
      int Hl = level_H(lvl), HWl = Hl * Hl;
      int a = n / HWl, rem = n - a * HWl, gy = rem / Hl, gx = rem - gy * Hl;
      const float* pred = (lvl == 0) ? pred0 : ((lvl == 1) ? pred1 : pred2);
      const float* p = pred + ((size_t)b * 4 * HWl + (size_t)n) * 6;
      float p0 = p[0], p1 = p[1], p2 = p[2], p3 = p[3];
      float aw = c_anc[lvl][a][0], ah = c_anc[lvl][a][1];
      float x = p0 * aw + (float)gx;
      float y = p1 * ah + (float)gy;
      float wv = expf(p2) * aw;
      float hv = expf(p3) * ah;
      float sc = c_scale[lvl];
      float x1 = fminf(fmaxf((x - 0.5f * wv) * sc, 0.0f), 1.0f);
      float y1 = fminf(fmaxf((y - 0.5f * hv) * sc, 0.0f), 1.0f);
      float x2 = fminf(fmaxf((x + 0.5f * wv) * sc, 0.0f), 1.0f);
      float y2 = fminf(fmaxf((y + 0.5f * hv) * sc, 0.0f), 1.0f);
      float* Bx = ws_box + (size_t)b * BOX_IMG;
      Bx[rank] = x1;
      Bx[BOX_STRIDE + rank] = y1;
      Bx[2 * BOX_STRIDE + rank] = x2;
      Bx[3 * BOX_STRIDE + rank] = y2;
      Bx[4 * BOX_STRIDE + rank] = sv;
      ((int*)(Bx + 5 * BOX_STRIDE))[rank] = slot;
    }
    __syncthreads();
  }
  grid.sync();

  // ---------------- P5: transposed IoU suppression mask (240 units) ----------------
  for (int u = blk; u < 240; u += nblk) {
    const int w = u % 15, b = u / 15;
    const float* B = ws_box + (size_t)b * BOX_IMG;
    const float* X1 = B, * Y1 = B + BOX_STRIDE, * X2 = B + 2 * BOX_STRIDE, * Y2 = B + 3 * BOX_STRIDE;
    const int Np = cnt[b * 3] + cnt[b * 3 + 1] + cnt[b * 3 + 2];
    if (t < 64) {
      int j = w * 64 + t;
      if (j < Np) {
        float a1 = X1[j], b1 = Y1[j], a2 = X2[j], b2 = Y2[j];
        sh_jx1[t] = a1; sh_jy1[t] = b1; sh_jx2[t] = a2; sh_jy2[t] = b2;
        sh_jar[t] = (a2 - a1) * (b2 - b1);
      }
    }
    __syncthreads();
    u64* mk = maskT + (size_t)b * MASK_IMG + (size_t)w * MASKT_STRIDE;
    const int j0 = w << 6;
    const int jlim = min(64, Np - j0);
    for (int i = t; i < MASKT_STRIDE; i += 256) {
      u64 bits = 0;
      if (i < Np && jlim > 0 && j0 + 63 > i) {
        float xi1 = X1[i], yi1 = Y1[i], xi2 = X2[i], yi2 = Y2[i];
        float ai = (xi2 - xi1) * (yi2 - yi1);
        for (int jj = 0; jj < jlim; ++jj) {
          int j = j0 + jj;
          if (j > i) {
            float xx1 = fmaxf(xi1, sh_jx1[jj]);
            float yy1 = fmaxf(yi1, sh_jy1[jj]);
            float xx2 = fminf(xi2, sh_jx2[jj]);
            float yy2 = fminf(yi2, sh_jy2[jj]);
            float iw = fmaxf(xx2 - xx1, 0.0f);
            float ih = fmaxf(yy2 - yy1, 0.0f);
            float inter = iw * ih;
            float iou = inter / (ai + sh_jar[jj] - inter + 1e-9f);
            if (iou > 0.45f) bits |= (1ull << jj);
          }
        }
      }
      mk[i] = bits;
    }
    __syncthreads();
  }
  grid.sync();

  // ---------------- P6: greedy NMS scan (16 units, wave 0 of block) ----------------
  for (int u = blk; u < 16; u += nblk) {
    if (t < 64) {
      const int b = u;
      const int Np = cnt[b * 3] + cnt[b * 3 + 1] + cnt[b * 3 + 2];
      const u64* mkT = maskT + (size_t)b * MASK_IMG;

#define DECL_DIAG(c) u64 d##c = mkT[(size_t)(c) * MASKT_STRIDE + (c) * 64 + lane];
      DECL_DIAG(0) DECL_DIAG(1) DECL_DIAG(2) DECL_DIAG(3) DECL_DIAG(4)
      DECL_DIAG(5) DECL_DIAG(6) DECL_DIAG(7) DECL_DIAG(8) DECL_DIAG(9)
      DECL_DIAG(10) DECL_DIAG(11) DECL_DIAG(12) DECL_DIAG(13) DECL_DIAG(14)
#undef DECL_DIAG

      u64 remv = 0, keepw = 0;
      u32 tot = 0;
      const bool ldok = (lane < 15);

      // per tile: issue column loads FIRST (independent of keep), serial closure
      // runs during the load latency, then predicated accumulate.
#define TILE(c, dvar) \
      if ((c) * 64 < Np && tot < (u32)MAXPROP) { \
        u64 cw[64]; \
        { \
          const u64* colw_ = mkT + (size_t)lane * MASKT_STRIDE + (c) * 64; \
          const bool ld_ = ldok && (lane > (c)); \
          _Pragma("unroll") \
          for (int k = 0; k < 64; ++k) cw[k] = ld_ ? colw_[k] : 0ull; \
        } \
        u64 rv = readlane_u64(remv, (c)); \
        int rem_ = Np - (c) * 64; \
        u64 valid_ = (rem_ >= 64) ? ~0ull : ((1ull << rem_) - 1ull); \
        u64 live = valid_ & ~rv; \
        u64 keep = 0; \
        while (live) { \
          int j_ = (int)__builtin_ctzll(live); \
          keep |= (1ull << j_); \
          u64 row_ = readlane_u64(dvar, j_); \
          live &= ~(row_ | (1ull << j_)); \
        } \
        if (lane == (c)) keepw = keep; \
        u64 acc_ = 0; \
        _Pragma("unroll") \
        for (int k = 0; k < 64; ++k) acc_ |= ((keep >> k) & 1ull) ? cw[k] : 0ull; \
        remv |= acc_; \
        tot += (u32)__popcll(keep); \
      }

      TILE(0, d0) TILE(1, d1) TILE(2, d2) TILE(3, d3) TILE(4, d4)
      TILE(5, d5) TILE(6, d6) TILE(7, d7) TILE(8, d8) TILE(9, d9)
      TILE(10, d10) TILE(11, d11) TILE(12, d12) TILE(13, d13) TILE(14, d14)
#undef TILE

      // keep-word prefix + compaction, all within wave 0 via readlane
      u32 pc = (lane < 15) ? (u32)__popcll(keepw) : 0u;
      u32 incl = pc;
      #pragma unroll
      for (int off = 1; off < 64; off <<= 1) { u32 v = __shfl_up(incl, (unsigned)off, 64); if (lane >= off) incl += v; }
      u32 excl = incl - pc;
      int* src = ws_src + b * MAXPROP;
      for (int r = lane; r < MAXPROP; r += 64) src[r] = -1;
      for (int i = lane; i < Np; i += 64) {
        int w = i >> 6;                       // uniform across the wave per iteration
        u64 kw = readlane_u64(keepw, w);
        u32 pre = (u32)__builtin_amdgcn_readlane((int)excl, w);
        if ((kw >> (i & 63)) & 1ull) {
          u32 rank = pre + (u32)__popcll(kw & ((1ull << (i & 63)) - 1ull));
          if (rank < MAXPROP) src[rank] = i;
        }
      }
    }
    __syncthreads();
  }
  grid.sync();

  // ---------------- P7: output rows (one wave per row, grid-stride) ----------------
  for (int task = blk * 4 + wid; task < 16 * MAXPROP; task += nblk * 4) {
    const int b = task / MAXPROP;
    const int r = task - b * MAXPROP;
    float* orow = out + ((size_t)b * MAXPROP + r) * DDIM;
    const int i = ws_src[b * MAXPROP + r];
    if (i < 0) {
      for (int c = lane; c < DDIM; c += 64) orow[c] = 0.0f;
      continue;
    }
    const float* B = ws_box + (size_t)b * BOX_IMG;
    float x1 = B[i], y1 = B[BOX_STRIDE + i], x2 = B[2 * BOX_STRIDE + i], y2 = B[3 * BOX_STRIDE + i];
    float score = B[4 * BOX_STRIDE + i];
    int slot = ((const int*)(B + 5 * BOX_STRIDE))[i];
    int n = sel_idx[(size_t)b * NPROP + slot];
    int lvl = slot / KLVL;
    int Hl = level_H(lvl), HWl = Hl * Hl;
    int a = n / HWl, rem = n - a * HWl, gy = rem / Hl, gx = rem - gy * Hl;
    (void)a;
    const float* emb = (lvl == 0) ? emb0 : ((lvl == 1) ? emb1 : emb2);
    const float* e = emb + ((size_t)(b * Hl + gy) * Hl + gx) * EDIM;
    float v0 = e[lane], v1 = e[lane + 64], v2 = e[lane + 128];
    float v3 = (lane < 16) ? e[lane + 192] : 0.0f;
    float ss = v0 * v0 + v1 * v1 + v2 * v2 + v3 * v3;
    for (int off = 32; off > 0; off >>= 1) ss += __shfl_xor(ss, off, 64);
    float rs = 1.0f / sqrtf(fmaxf(ss, 1e-12f));
    if (lane == 0) {
      orow[0] = x1; orow[1] = y1; orow[2] = x2; orow[3] = y2; orow[4] = score;
    }
    orow[5 + lane] = v0 * rs;
    orow[5 + 64 + lane] = v1 * rs;
    orow[5 + 128 + lane] = v2 * rs;
    if (lane < 16) orow[5 + 192 + lane] = v3 * rs;
  }
}

// ---------------------------------------------------------------------------
extern "C" void kernel_launch(void* const* d_in, const int* in_sizes, int n_in,
                              void* d_out, int out_size, void* d_ws, size_t ws_size,
                              hipStream_t stream) {
  const float* pred[3] = {nullptr, nullptr, nullptr};
  const float* emb[3] = {nullptr, nullptr, nullptr};
  for (int i = 0; i < n_in; ++i) {
    const float* p = (const float*)d_in[i];
    switch (in_sizes[i]) {
      case 2217984:  pred[0] = p; break;   // 16*4*76*76*6
      case 554496:   pred[1] = p; break;   // 16*4*38*38*6
      case 138624:   pred[2] = p; break;   // 16*4*19*19*6
      case 19222528: emb[0] = p; break;    // 16*76*76*208
      case 4805632:  emb[1] = p; break;    // 16*38*38*208
      case 1201408:  emb[2] = p; break;    // 16*19*19*208
      default: break;
    }
  }
  const float* p0 = pred[0]; const float* p1 = pred[1]; const float* p2 = pred[2];
  const float* e0 = emb[0];  const float* e1 = emb[1];  const float* e2 = emb[2];
  char* wsp = (char*)d_ws;
  float* op = (float*)d_out;

  int grid = 512;
  int nb = 0;
  if (hipOccupancyMaxActiveBlocksPerMultiprocessor(&nb, (const void*)proposal_mega_kernel, 256, 0) == hipSuccess && nb > 0) {
    int g = nb * 256;                 // 256 CUs on MI355X
    if (g < grid) grid = g;
  } else {
    grid = 256;
  }

  void* args[] = {(void*)&p0, (void*)&p1, (void*)&p2, (void*)&e0, (void*)&e1, (void*)&e2,
                  (void*)&wsp, (void*)&op};
  hipLaunchCooperativeKernel((const void*)proposal_mega_kernel, dim3(grid), dim3(256),
                             args, 0, stream);
}